// Round 5
// baseline (1168.157 us; speedup 1.0000x reference)
//
#include <hip/hip_runtime.h>
#include <math.h>

#define B_      1024
#define V_      50257
#define ROUNDS_ 32
#define NT      256
#define NW      4
#define NC      197   // ceil(V_/256)

// Hillis-Steele inclusive scan across 64 lanes (f32)
__device__ __forceinline__ float hs_scan_f(float x, int lane) {
  #pragma unroll
  for (int d = 1; d < 64; d <<= 1) {
    float o = __shfl_up(x, d);
    if (lane >= d) x += o;
  }
  return x;
}

struct Shm {
  float sC[NC];     // chunk sums of truncated f32 probs (scan-order-consistent)
  float pf[NC];     // exclusive f32 prefix of chunk sums
  float pMax[NC];   // chunk max prob (exact sparse-skip)
  float pbuf[256];  // replay staging
  float wRedF[NW];
  int   wRedI[NW];
  float Z, S;
  int   cs, idx, crossed, cnt;
};

__global__ __launch_bounds__(NT) void sampler_kernel(
    const float* __restrict__ logits,
    const float* __restrict__ temp,
    const float* __restrict__ topp,
    const float* __restrict__ uni,
    const int*   __restrict__ topk,
    int* __restrict__ out)
{
  __shared__ Shm sh;
  const int row  = blockIdx.x;
  const int tid  = threadIdx.x;
  const int lane = tid & 63;
  const int wave = tid >> 6;
  const float* __restrict__ L = logits + (size_t)row * V_;

  const float T    = temp[0];
  const float topP = topp[0];
  const int   K    = topk[0];

  // ---------- P1: m = f32 max of l/T (exact, order-free) ----------
  float mloc = -INFINITY;
  for (int j = tid; j < V_; j += NT) mloc = fmaxf(mloc, L[j] / T);
  #pragma unroll
  for (int d = 32; d; d >>= 1) mloc = fmaxf(mloc, __shfl_xor(mloc, d));
  if (lane == 0) sh.wRedF[wave] = mloc;
  __syncthreads();
  const float m = fmaxf(fmaxf(sh.wRedF[0], sh.wRedF[1]),
                        fmaxf(sh.wRedF[2], sh.wRedF[3]));

  auto EF = [&](int j) -> float {             // f32-quantized e, CR exp
    float y = L[j] / T;
    return (float)exp((double)(y - m));
  };

  // ---------- P2: chunk e-sums + eMax -> Z (f32 tree), pMax ----------
  for (int c = wave; c < NC; c += NW) {
    float es = 0.f, em = 0.f;
    #pragma unroll
    for (int s = 0; s < 4; ++s) {
      int j = (c << 8) + (s << 6) + lane;
      if (j < V_) { float e = EF(j); es += e; em = fmaxf(em, e); }
    }
    #pragma unroll
    for (int d = 32; d; d >>= 1) {
      es += __shfl_xor(es, d);
      em = fmaxf(em, __shfl_xor(em, d));
    }
    if (lane == 0) { sh.sC[c] = es; sh.pMax[c] = em; }
  }
  __syncthreads();
  if (wave == 0) {
    int i0 = lane << 2;
    float a = 0.f;
    #pragma unroll
    for (int t = 0; t < 4; ++t) if (i0 + t < NC) a += sh.sC[i0 + t];
    #pragma unroll
    for (int d = 32; d; d >>= 1) a += __shfl_xor(a, d);
    if (lane == 0) sh.Z = a;
  }
  __syncthreads();
  const float Z = sh.Z;
  for (int c = tid; c < NC; c += NT) sh.pMax[c] = sh.pMax[c] / Z;  // monotone: exact max(p)
  __syncthreads();

  auto PF = [&](int j) -> float { return EF(j) / Z; };  // f32 prob

  // ---------- chunk pass: scan-consistent chunk sums + exact counts ----------
  auto chunk_pass = [&](float pivp, bool skip) {
    int myCnt = 0;
    for (int c = wave; c < NC; c += NW) {
      bool live = (!skip) || (sh.pMax[c] > pivp);   // wave-uniform (LDS value)
      if (live) {
        float run = 0.f;
        #pragma unroll
        for (int s = 0; s < 4; ++s) {
          int j = (c << 8) + (s << 6) + lane;
          float p = (j < V_) ? PF(j) : 0.0f;
          bool g = (j < V_) && (p > pivp);
          float q = g ? p : 0.0f;
          myCnt += __popcll(__ballot(g));
          float x = hs_scan_f(q, lane);
          run += __shfl(x, 63);                 // serial carry = replay order
        }
        if (lane == 0) sh.sC[c] = run;
      } else if (lane == 0) {
        sh.sC[c] = 0.f;
      }
    }
    if (lane == 0) sh.wRedI[wave] = myCnt;
    __syncthreads();
    if (wave == 0) {                            // chunk-prefix: serial-4 + H-S tree
      int i0 = lane << 2;
      float v0 = (i0     < NC) ? sh.sC[i0    ] : 0.f;
      float v1 = (i0 + 1 < NC) ? sh.sC[i0 + 1] : 0.f;
      float v2 = (i0 + 2 < NC) ? sh.sC[i0 + 2] : 0.f;
      float v3 = (i0 + 3 < NC) ? sh.sC[i0 + 3] : 0.f;
      float e1 = v0, e2 = e1 + v1, e3 = e2 + v2, lt = e3 + v3;
      float runh = hs_scan_f(lt, lane);
      float excl = __shfl_up(runh, 1);
      if (lane == 0) excl = 0.f;
      if (i0     < NC) sh.pf[i0    ] = excl;
      if (i0 + 1 < NC) sh.pf[i0 + 1] = excl + e1;
      if (i0 + 2 < NC) sh.pf[i0 + 2] = excl + e2;
      if (i0 + 3 < NC) sh.pf[i0 + 3] = excl + e3;
      if (lane == 63) sh.S = runh;
      if (lane == 0)
        sh.cnt = sh.wRedI[0] + sh.wRedI[1] + sh.wRedI[2] + sh.wRedI[3];
    }
    __syncthreads();
  };

  chunk_pass(-1.0f, false);   // round-0 cdf (all p > -1; p>0 always)

  float pivot = 0.0f;
  int   token = 0;

  for (int r = 0; r < ROUNDS_; ++r) {
    const float S      = sh.S;
    const float target = uni[r * B_ + row] * S;   // f32 mul

    // crossing chunk = #chunks with inclusive boundary < target
    bool flag = (tid < NC) && (sh.pf[tid] + sh.sC[tid] < target);
    unsigned long long bal = __ballot(flag);
    if (lane == 0) sh.wRedI[wave] = __popcll(bal);
    __syncthreads();
    if (tid == 0) {
      int c = sh.wRedI[0] + sh.wRedI[1] + sh.wRedI[2] + sh.wRedI[3];
      sh.cs = (c > NC - 1) ? (NC - 1) : c;
      sh.crossed = 0;
      sh.idx = V_ - 1;
    }
    __syncthreads();

    // self-consistent replay, rolls into following chunks on 1-ulp boundary slip
    const int rc = sh.cs;
    float rrun = (wave == 0) ? sh.pf[rc] : 0.f;
    int   acc  = 0;
    for (int itc = rc; itc < NC; ++itc) {
      int j = (itc << 8) + tid;
      sh.pbuf[tid] = (j < V_) ? PF(j) : 0.0f;
      __syncthreads();
      if (wave == 0) {
        int len = min(256, V_ - (itc << 8));
        int ccount = 0;
        #pragma unroll
        for (int s = 0; s < 4; ++s) {
          int jl = (s << 6) + lane;
          int jg = (itc << 8) + jl;
          float p = sh.pbuf[jl];
          float q = (jg < V_ && p > pivot) ? p : 0.0f;
          float x = hs_scan_f(q, lane);
          bool cf = (jg < V_) && (rrun + x < target);
          ccount += __popcll(__ballot(cf));
          rrun += __shfl(x, 63);
        }
        acc += ccount;
        if (ccount < len && lane == 0) {   // crossed inside this chunk
          int idx = (rc << 8) + acc;
          if (idx > V_ - 1) idx = V_ - 1;
          sh.idx = idx;
          sh.crossed = 1;
        }
      }
      __syncthreads();
      if (sh.crossed) break;               // uniform (read after barrier)
    }
    __syncthreads();
    token = sh.idx;                         // "record last sample" semantics
    const float pv = PF(token);             // == probs[idx] in my f32 pipeline

    // accept stats vs pv; doubles as next round's truncated cdf
    chunk_pass(pv, true);

    if (sh.cnt < K && sh.S < topP) break;   // accepted -> frozen
    pivot = pv;
  }

  if (tid == 0) out[row] = token;
}

extern "C" void kernel_launch(void* const* d_in, const int* in_sizes, int n_in,
                              void* d_out, int out_size, void* d_ws, size_t ws_size,
                              hipStream_t stream) {
  const float* logits = (const float*)d_in[0];
  const float* temp   = (const float*)d_in[1];
  const float* topp   = (const float*)d_in[2];
  const float* uni    = (const float*)d_in[3];
  const int*   topk   = (const int*)d_in[4];
  int* out = (int*)d_out;
  (void)in_sizes; (void)n_in; (void)out_size; (void)d_ws; (void)ws_size;
  sampler_kernel<<<B_, NT, 0, stream>>>(logits, temp, topp, uni, topk, out);
}